// Round 9
// baseline (146.193 us; speedup 1.0000x reference)
//
#include <hip/hip_runtime.h>
#include <hip/hip_bf16.h>

#define NROWS 16384
#define DIM   256
#define DB    (DIM / 2)               // 128 bytes per fp4 row
#define SEGS  8
#define BN    128                     // tile: 128 cols x 256 k (fp4) = 16 KB
#define TB    (BN * DB)               // 16384 bytes per tile
#define NT    ((NROWS / SEGS) / BN)   // 16 tiles per segment
#define INVT  14.285714285714286f
#define C1f   20.60992915555662f      // log2(e)/0.07 ; A is pre-scaled by this
#define LN2f  0.6931471805599453f

typedef __attribute__((ext_vector_type(8)))  int   int8v;    // MFMA operand (fp4 uses low 4 regs)
typedef __attribute__((ext_vector_type(16))) float f32x16;   // 32x32 MFMA accumulator

#define SCA 0x7F7F7F7Fu   // E8M0 = 2^0   (A scale; A pre-scaled by C1, sigma~1.29)
#define SCB 0x7B7B7B7Bu   // E8M0 = 2^-4  (B scale; B pre-multiplied by 16, sigma~1.0)

// fp4 e2m1 RNE quantize: codes 0..7 = {0, .5, 1, 1.5, 2, 3, 4, 6} (monotonic), bit3 = sign
__device__ __forceinline__ unsigned fp4q(float v) {
    float a = fabsf(v);
    unsigned s = (__float_as_uint(v) >> 28) & 0x8u;
    unsigned idx = (unsigned)(a >= 0.25f) + (a >= 0.75f) + (a >= 1.25f) + (a >= 1.75f)
                 + (a >= 2.5f) + (a >= 3.5f) + (a >= 5.0f);
    return s | idx;
}

// Kernel 1: L2-normalize (fp32); emit fp4 A (row-major, xC1) and fp4 B (x16) in the
// chunked layout, plus exact fp32 diagonal. One wave per row; lane holds 4 values
// = 16 bits per matrix.
// B layout (16B chunks of the 128B fp4 row): chunk(col,kcb4) = (col>>7)*1024
//     + ((col>>6)&1)*512 + kcb4*64 + (col&63),   kcb4 = 16B chunk along K (0..7)
__global__ __launch_bounds__(256) void norm_diag_kernel(
    const float* __restrict__ fl, const float* __restrict__ fg,
    unsigned char* __restrict__ A, unsigned char* __restrict__ B,
    float* __restrict__ diag, float* __restrict__ out)
{
    int tid  = threadIdx.x;
    int wave = tid >> 6, lane = tid & 63;
    int row  = blockIdx.x * 4 + wave;
    if (blockIdx.x == 0 && tid == 0) out[0] = 0.0f;   // zero accumulator for final atomicAdd

    float4 xl = ((const float4*)(fl + (size_t)row * DIM))[lane];
    float4 xg = ((const float4*)(fg + (size_t)row * DIM))[lane];
    float ssl = xl.x*xl.x + xl.y*xl.y + xl.z*xl.z + xl.w*xl.w;
    float ssg = xg.x*xg.x + xg.y*xg.y + xg.z*xg.z + xg.w*xg.w;
    for (int m = 1; m < 64; m <<= 1) {
        ssl += __shfl_xor(ssl, m, 64);
        ssg += __shfl_xor(ssg, m, 64);
    }
    float il = 1.0f / fmaxf(sqrtf(ssl), 1e-12f);
    float ig = 1.0f / fmaxf(sqrtf(ssg), 1e-12f);
    float nl0 = xl.x*il, nl1 = xl.y*il, nl2 = xl.z*il, nl3 = xl.w*il;
    float ng0 = xg.x*ig, ng1 = xg.y*ig, ng2 = xg.z*ig, ng3 = xg.w*ig;

    // A: quantize C1*nl to fp4 (scale 2^0 at MFMA); lane holds k = 4*lane..4*lane+3
    unsigned pa4 = fp4q(nl0 * C1f) | (fp4q(nl1 * C1f) << 4)
                 | (fp4q(nl2 * C1f) << 8) | (fp4q(nl3 * C1f) << 12);
    ((unsigned short*)(A + (size_t)row * DB))[lane] = (unsigned short)pa4;

    // B: quantize 16*ng to fp4 (scale 2^-4 at MFMA), store into chunked layout
    unsigned pb4 = fp4q(ng0 * 16.0f) | (fp4q(ng1 * 16.0f) << 4)
                 | (fp4q(ng2 * 16.0f) << 8) | (fp4q(ng3 * 16.0f) << 12);
    {
        int kcb4 = lane >> 3;         // 16B chunk along K (0..7); lane's 2 bytes sit at (lane&7)*2
        unsigned chunk = (unsigned)((row >> 7) * 1024 + ((row >> 6) & 1) * 512
                                    + kcb4 * 64 + (row & 63));
        ((unsigned short*)B)[chunk * 8 + (lane & 7)] = (unsigned short)pb4;
    }

    float d = nl0*ng0 + nl1*ng1 + nl2*ng2 + nl3*ng3;   // exact fp32 diagonal
    for (int m = 1; m < 64; m <<= 1) d += __shfl_xor(d, m, 64);
    if (lane == 0) diag[row] = d;
}

// Kernel 2: fused sim-GEMM + fixed-max sumexp, MX-fp4 32x32x64 (fmt=4, 2x fp8 rate).
// R27 (resubmitted after broker timeout): DROP LDS STAGING ENTIRELY (catalog
// Common-mistake #7: staging L2-resident data is pure overhead — B is 2 MB, each
// XCD L2 is 4 MB). Evidence: R21 (2 waves/SIMD, 2-deep ILP) and R26 (~3.5 waves,
// 1-deep) both land at exactly 51.6 us with MfmaUtil 25-26 / VALUBusy 41-45 —
// neither occupancy nor issue order moves it; the invariant is the barrier-clocked
// DMA staging structure (per-tile __syncthreads + vmcnt(0) drain + 4x redundant
// LDS re-reads/CU). This version reads B fragments directly from global via the
// same chunked layout (per-wave reads are two contiguous 512B runs per instr):
// ZERO barriers, zero LDS, zero DMA. 4 waves/block share each 16 KB tile through
// L1 (32 KB); L2 serves the rest (B fully L2-resident). Waves run completely free.
// Reg footprint: af 32 + b0/b1 16 + acc 32 (AGPR) + lv 16 + addr ~12 -> ~110
// combined VGPR+AGPR, honestly under the 128 cap for 4 waves/SIMD.
__global__ __launch_bounds__(256, 4) void sim_lse_kernel(
    const unsigned char* __restrict__ A, const unsigned char* __restrict__ B,
    float* __restrict__ lpart)
{
    int tid  = threadIdx.x;
    int lane = tid & 63;
    int l31  = lane & 31, half = lane >> 5;
    int wave = tid >> 6;
    int seg  = blockIdx.x;
    int rowBase = blockIdx.y * 128 + wave * 32;   // 32 rows per wave

    const int4 zero4 = make_int4(0, 0, 0, 0);

    // Preload A fragments: lane(l31,half) holds A[m=rowBase+l31][k = kk*64 + half*32 + 0..31]
    // = 16 bytes of fp4; high half of the 8-reg operand is unused (fmt=4) -> zeroed once.
    int8v af[4];
    {
        const unsigned char* ap = A + (size_t)(rowBase + l31) * DB + half * 16;
#pragma unroll
        for (int kk = 0; kk < 4; ++kk) {
            ((int4*)&af[kk])[0] = *(const int4*)(ap + kk * 32);
            ((int4*)&af[kk])[1] = zero4;
        }
    }

    f32x16 lv;
    f32x16 accA, accB;
#pragma unroll
    for (int r = 0; r < 16; ++r) {
        lv[r] = -1.0f;     // compensate the one dummy epilogue (exp of accB=0)
        accB[r] = 0.0f;    // dummy-epilogue source
    }

#define MFMA4(dst, a, b, cin) \
    dst = __builtin_amdgcn_mfma_scale_f32_32x32x64_f8f6f4(a, b, cin, 4, 4, 0, SCA, 0, SCB)

    // One 32x32 unit: zero-init ac + 4 global 16B loads (L1/L2-served) + 4 MFMAs
    // + 16 exp2/add, source-interleaved. ac = compute target (this unit's columns);
    // ax = exp source (previous unit's acc).
    auto unit = [&](f32x16& ac, f32x16& ax, const unsigned char* bp, unsigned offc) {
#pragma unroll
        for (int r = 0; r < 16; ++r) ac[r] = 0.0f;
        int8v b0, b1;
        ((int4*)&b0)[1] = zero4; ((int4*)&b1)[1] = zero4;
        ((int4*)&b0)[0] = *(const int4*)(bp + offc);           // kk=0
        ((int4*)&b1)[0] = *(const int4*)(bp + offc + 2048u);   // kk=1
        MFMA4(ac, af[0], b0, ac);
        ((int4*)&b0)[0] = *(const int4*)(bp + offc + 4096u);   // kk=2
        MFMA4(ac, af[1], b1, ac);
#pragma unroll
        for (int r = 0; r < 8; ++r)
            lv[r] += __builtin_amdgcn_exp2f(ax[r]);
        ((int4*)&b1)[0] = *(const int4*)(bp + offc + 6144u);   // kk=3
        MFMA4(ac, af[2], b0, ac);
        MFMA4(ac, af[3], b1, ac);
#pragma unroll
        for (int r = 8; r < 16; ++r)
            lv[r] += __builtin_amdgcn_exp2f(ax[r]);
    };

    // Per-wave B base: lanes 0-31 read bytes [0,512) of a chunk-row, lanes 32-63
    // read [1024,1536) — same addressing as the former LDS image (byte-identical
    // layout, tile t at byte offset t*TB).
    const unsigned char* bw = B + (size_t)seg * NT * TB
                            + (unsigned)(l31 * 16 + half * 1024);

    for (int t = 0; t < NT; ++t) {
        const unsigned char* bp = bw + (size_t)t * TB;
        unit(accA, accB, bp, 0u);      // cols  0-31, exp prev accB
        unit(accB, accA, bp, 512u);    // cols 32-63, exp accA just computed
        unit(accA, accB, bp, 8192u);   // cols 64-95 (sub-tile 1)
        unit(accB, accA, bp, 8704u);   // cols 96-127
    }
    // final epilogue: exp the last computed accB
#pragma unroll
    for (int r = 0; r < 16; ++r)
        lv[r] += __builtin_amdgcn_exp2f(accB[r]);

    // Sum across the 32 column-lanes
#pragma unroll
    for (int r = 0; r < 16; ++r) {
        float v = lv[r];
        v += __shfl_xor(v, 1, 64);
        v += __shfl_xor(v, 2, 64);
        v += __shfl_xor(v, 4, 64);
        v += __shfl_xor(v, 8, 64);
        v += __shfl_xor(v, 16, 64);
        lv[r] = v;
    }
    if (l31 == 0) {
#pragma unroll
        for (int r = 0; r < 16; ++r) {
            int row = rowBase + (r & 3) + 8*(r >> 2) + 4*half;
            lpart[(size_t)seg * NROWS + row] = lv[r];
        }
    }
#undef MFMA4
}

// Kernel 3: loss_i = -invT*diag_i + ln2*log2(sum_seg l_part), then mean via atomicAdd.
__global__ __launch_bounds__(256) void reduce_kernel(
    const float* __restrict__ lpart, const float* __restrict__ diag,
    float* __restrict__ out)
{
    __shared__ float sm[4];
    int gtid = blockIdx.x * 256 + threadIdx.x;
    float s = 0.0f;
    for (int row = gtid; row < NROWS; row += 32 * 256) {
        float t = 0.0f;
#pragma unroll
        for (int g = 0; g < SEGS; ++g) t += lpart[(size_t)g * NROWS + row];
        s += LN2f * log2f(t) - INVT * diag[row];
    }
    for (int m = 1; m < 64; m <<= 1) s += __shfl_xor(s, m, 64);
    int wave = threadIdx.x >> 6, lane = threadIdx.x & 63;
    if (lane == 0) sm[wave] = s;
    __syncthreads();
    if (threadIdx.x == 0) {
        float tot = sm[0] + sm[1] + sm[2] + sm[3];
        atomicAdd(out, tot * (1.0f / NROWS));
    }
}

extern "C" void kernel_launch(void* const* d_in, const int* in_sizes, int n_in,
                              void* d_out, int out_size, void* d_ws, size_t ws_size,
                              hipStream_t stream) {
    const float* fl = (const float*)d_in[0];
    const float* fg = (const float*)d_in[1];
    float* out = (float*)d_out;

    char* ws = (char*)d_ws;
    unsigned char* A = (unsigned char*)ws;                         // 16384*128 = 2 MB (fp4)
    unsigned char* B = A + (size_t)NROWS * DB;                     // 2 MB (fp4, chunked layout)
    float* diag  = (float*)(ws + 2 * (size_t)NROWS * DB);          // 64 KB
    float* lpart = diag + NROWS;                                   // SEGS*N*4 = 512 KB

    norm_diag_kernel<<<NROWS / 4, 256, 0, stream>>>(fl, fg, A, B, diag, out);
    sim_lse_kernel<<<dim3(SEGS, NROWS / 128), 256, 0, stream>>>(A, B, lpart);
    reduce_kernel<<<32, 256, 0, stream>>>(lpart, diag, out);
}

// Round 10
// 135.081 us; speedup vs baseline: 1.0823x; 1.0823x over previous
//
#include <hip/hip_runtime.h>
#include <hip/hip_bf16.h>

#define NROWS 16384
#define DIM   256
#define DB    (DIM / 2)               // 128 bytes per fp4 row
#define SEGS  8
#define BN    128                     // staged tile: 128 cols x 256 k (fp4) = 16 KB
#define TB    (BN * DB)               // 16384 bytes per staged tile
#define NT    ((NROWS / SEGS) / BN)   // 16 tiles per segment
#define INVT  14.285714285714286f
#define C1f   20.60992915555662f      // log2(e)/0.07 ; A is pre-scaled by this
#define LN2f  0.6931471805599453f

typedef __attribute__((ext_vector_type(8)))  int   int8v;    // MFMA operand (fp4 uses low 4 regs)
typedef __attribute__((ext_vector_type(16))) float f32x16;   // 32x32 MFMA accumulator

#define SCA 0x7F7F7F7Fu   // E8M0 = 2^0   (A scale; A pre-scaled by C1, sigma~1.29)
#define SCB 0x7B7B7B7Bu   // E8M0 = 2^-4  (B scale; B pre-multiplied by 16, sigma~1.0)

// fp4 e2m1 RNE quantize: codes 0..7 = {0, .5, 1, 1.5, 2, 3, 4, 6} (monotonic), bit3 = sign
__device__ __forceinline__ unsigned fp4q(float v) {
    float a = fabsf(v);
    unsigned s = (__float_as_uint(v) >> 28) & 0x8u;
    unsigned idx = (unsigned)(a >= 0.25f) + (a >= 0.75f) + (a >= 1.25f) + (a >= 1.75f)
                 + (a >= 2.5f) + (a >= 3.5f) + (a >= 5.0f);
    return s | idx;
}

// Kernel 1: L2-normalize (fp32); emit fp4 A (row-major, xC1) and fp4 B (x16) in the
// DMA staging layout, plus exact fp32 diagonal. One wave per row; lane holds 4 values
// = 16 bits per matrix.
// B layout (16B chunks of the 128B fp4 row): chunk(col,kcb4) = (col>>7)*1024
//     + ((col>>6)&1)*512 + kcb4*64 + (col&63),   kcb4 = 16B chunk along K (0..7)
__global__ __launch_bounds__(256) void norm_diag_kernel(
    const float* __restrict__ fl, const float* __restrict__ fg,
    unsigned char* __restrict__ A, unsigned char* __restrict__ B,
    float* __restrict__ diag, float* __restrict__ out)
{
    int tid  = threadIdx.x;
    int wave = tid >> 6, lane = tid & 63;
    int row  = blockIdx.x * 4 + wave;
    if (blockIdx.x == 0 && tid == 0) out[0] = 0.0f;   // zero accumulator for final atomicAdd

    float4 xl = ((const float4*)(fl + (size_t)row * DIM))[lane];
    float4 xg = ((const float4*)(fg + (size_t)row * DIM))[lane];
    float ssl = xl.x*xl.x + xl.y*xl.y + xl.z*xl.z + xl.w*xl.w;
    float ssg = xg.x*xg.x + xg.y*xg.y + xg.z*xg.z + xg.w*xg.w;
    for (int m = 1; m < 64; m <<= 1) {
        ssl += __shfl_xor(ssl, m, 64);
        ssg += __shfl_xor(ssg, m, 64);
    }
    float il = 1.0f / fmaxf(sqrtf(ssl), 1e-12f);
    float ig = 1.0f / fmaxf(sqrtf(ssg), 1e-12f);
    float nl0 = xl.x*il, nl1 = xl.y*il, nl2 = xl.z*il, nl3 = xl.w*il;
    float ng0 = xg.x*ig, ng1 = xg.y*ig, ng2 = xg.z*ig, ng3 = xg.w*ig;

    // A: quantize C1*nl to fp4 (scale 2^0 at MFMA); lane holds k = 4*lane..4*lane+3
    unsigned pa4 = fp4q(nl0 * C1f) | (fp4q(nl1 * C1f) << 4)
                 | (fp4q(nl2 * C1f) << 8) | (fp4q(nl3 * C1f) << 12);
    ((unsigned short*)(A + (size_t)row * DB))[lane] = (unsigned short)pa4;

    // B: quantize 16*ng to fp4 (scale 2^-4 at MFMA), store into staging layout
    unsigned pb4 = fp4q(ng0 * 16.0f) | (fp4q(ng1 * 16.0f) << 4)
                 | (fp4q(ng2 * 16.0f) << 8) | (fp4q(ng3 * 16.0f) << 12);
    {
        int kcb4 = lane >> 3;         // 16B chunk along K (0..7); lane's 2 bytes sit at (lane&7)*2
        unsigned chunk = (unsigned)((row >> 7) * 1024 + ((row >> 6) & 1) * 512
                                    + kcb4 * 64 + (row & 63));
        ((unsigned short*)B)[chunk * 8 + (lane & 7)] = (unsigned short)pb4;
    }

    float d = nl0*ng0 + nl1*ng1 + nl2*ng2 + nl3*ng3;   // exact fp32 diagonal
    for (int m = 1; m < 64; m <<= 1) d += __shfl_xor(d, m, 64);
    if (lane == 0) diag[row] = d;
}

// Kernel 2: fused sim-GEMM + fixed-max sumexp, MX-fp4 32x32x64 (fmt=4, 2x fp8 rate).
// R28: K-SPLIT DUAL-CHAIN on the proven R26 staging skeleton. Evidence synthesis:
// MfmaUtil x dur is constant (~13 us MFMA work) across R21/R26/R27; dur tracks
// independent-MFMA-stream count, not occupancy (R21: 2 waves x 2 chains = R26:
// 3.5 x 1 = 51.6 us) and global-direct loads lengthen the chain (R27: 69 us).
// The 4-deep dependent MFMA chain (issue ~35, latency ~140 cyc) needs >=4-6
// independent streams to fill the pipe; we had ~3.5. This version splits each
// unit's K=256 into two independent depth-2 chains (acc0: K 0-127, acc1:
// K 128-255), merged into the exp-source accP at unit end -> ~4 waves x 2 chains
// = 8 streams. Register cost: AGPR 32->48 (acc0,acc1,accP), VGPR ~64 unchanged,
// combined ~112 < 128 cap for 4 waves/SIMD (no spill). Staging, barriers, grid
// (8 segs x 128 row-blocks = 4 blocks/CU), LDS 32KB all unchanged from R26.
__global__ __launch_bounds__(256, 4) void sim_lse_kernel(
    const unsigned char* __restrict__ A, const unsigned char* __restrict__ B,
    float* __restrict__ lpart)
{
    __shared__ __align__(16) unsigned char bt[2 * TB];   // 2 x 16 KB double buffer

    int tid  = threadIdx.x;
    int lane = tid & 63;
    int l31  = lane & 31, half = lane >> 5;
    int wave = tid >> 6;
    int seg  = blockIdx.x;
    int rowBase = blockIdx.y * 128 + wave * 32;   // 32 rows per wave

    // LDS read base; unit offsets are 16-bit immediates:
    // addr = vb + bufo(16384) + s64*8192 + c*512 + kk*2048
    unsigned vb = (unsigned)(l31 * 16 + half * 1024);

    const int4 zero4 = make_int4(0, 0, 0, 0);

    // Preload A fragments: lane(l31,half) holds A[m=rowBase+l31][k = kk*64 + half*32 + 0..31]
    // = 16 bytes of fp4; high half of the 8-reg operand is unused (fmt=4) -> zeroed once.
    int8v af[4];
    {
        const unsigned char* ap = A + (size_t)(rowBase + l31) * DB + half * 16;
#pragma unroll
        for (int kk = 0; kk < 4; ++kk) {
            ((int4*)&af[kk])[0] = *(const int4*)(ap + kk * 32);
            ((int4*)&af[kk])[1] = zero4;
        }
    }

    f32x16 lv;
    f32x16 acc0, acc1, accP;
#pragma unroll
    for (int r = 0; r < 16; ++r) {
        lv[r] = -1.0f;     // compensate the one dummy epilogue (exp of accP=0)
        accP[r] = 0.0f;    // dummy exp source for the first unit
    }

    int T0 = seg * NT;

    // Stage one 16 KB tile (1024 16B chunks); each thread moves 4 chunks
    auto stage = [&](int T, unsigned bufo) {
        const unsigned char* g = B + (size_t)T * TB + (unsigned)tid * 16;
        unsigned lo = bufo + (unsigned)tid * 16;
#pragma unroll
        for (int j = 0; j < 4; ++j) {
            __builtin_amdgcn_global_load_lds(
                (const __attribute__((address_space(1))) unsigned int*)(g + j * 4096),
                (__attribute__((address_space(3))) unsigned int*)&bt[lo + j * 4096],
                16, 0, 0);
        }
    };

#define MFMA4(dst, a, b, cin) \
    dst = __builtin_amdgcn_mfma_scale_f32_32x32x64_f8f6f4(a, b, cin, 4, 4, 0, SCA, 0, SCB)

    // One 32x32 unit, K split into two independent depth-2 MFMA chains:
    //   chain0: kk=0,1 -> acc0     chain1: kk=2,3 -> acc1
    // exps consume accP (previous unit's merged result); at unit end accP = acc0+acc1.
    auto unit = [&](unsigned ab, unsigned offc) {
        int8v b0, b1;
        ((int4*)&b0)[1] = zero4; ((int4*)&b1)[1] = zero4;
        ((int4*)&b0)[0] = *(const int4*)&bt[ab + offc];           // kk=0 (chain0)
        ((int4*)&b1)[0] = *(const int4*)&bt[ab + offc + 4096u];   // kk=2 (chain1)
#pragma unroll
        for (int r = 0; r < 16; ++r) { acc0[r] = 0.0f; acc1[r] = 0.0f; }  // fills ds_read shadow
        MFMA4(acc0, af[0], b0, acc0);     // chain0 depth 1
        MFMA4(acc1, af[2], b1, acc1);     // chain1 depth 1 (independent)
#pragma unroll
        for (int r = 0; r < 8; ++r)
            lv[r] += __builtin_amdgcn_exp2f(accP[r]);
        ((int4*)&b0)[0] = *(const int4*)&bt[ab + offc + 2048u];   // kk=1
        ((int4*)&b1)[0] = *(const int4*)&bt[ab + offc + 6144u];   // kk=3
        MFMA4(acc0, af[1], b0, acc0);     // chain0 depth 2
        MFMA4(acc1, af[3], b1, acc1);     // chain1 depth 2
#pragma unroll
        for (int r = 8; r < 16; ++r)
            lv[r] += __builtin_amdgcn_exp2f(accP[r]);
        // merge: new exp source for the next unit (accP's old value fully consumed)
#pragma unroll
        for (int r = 0; r < 16; ++r)
            accP[r] = acc0[r] + acc1[r];
    };

    stage(T0, 0);

    for (int t = 0; t < NT; ++t) {
        unsigned bufo = (t & 1) ? (unsigned)TB : 0u;
        __syncthreads();   // drains own tile-t DMA (in flight a full tile), syncs waves

        if (t + 1 < NT)
            stage(T0 + t + 1, (t & 1) ? 0u : (unsigned)TB);

        unsigned ab = vb + bufo;
        unit(ab, 0u);      // cols  0-31
        unit(ab, 512u);    // cols 32-63
        unit(ab, 8192u);   // cols 64-95 (sub-tile 1)
        unit(ab, 8704u);   // cols 96-127
    }
    // final epilogue: exp the last unit's merged result
#pragma unroll
    for (int r = 0; r < 16; ++r)
        lv[r] += __builtin_amdgcn_exp2f(accP[r]);

    // Sum across the 32 column-lanes
#pragma unroll
    for (int r = 0; r < 16; ++r) {
        float v = lv[r];
        v += __shfl_xor(v, 1, 64);
        v += __shfl_xor(v, 2, 64);
        v += __shfl_xor(v, 4, 64);
        v += __shfl_xor(v, 8, 64);
        v += __shfl_xor(v, 16, 64);
        lv[r] = v;
    }
    if (l31 == 0) {
#pragma unroll
        for (int r = 0; r < 16; ++r) {
            int row = rowBase + (r & 3) + 8*(r >> 2) + 4*half;
            lpart[(size_t)seg * NROWS + row] = lv[r];
        }
    }
#undef MFMA4
}

// Kernel 3: loss_i = -invT*diag_i + ln2*log2(sum_seg l_part), then mean via atomicAdd.
__global__ __launch_bounds__(256) void reduce_kernel(
    const float* __restrict__ lpart, const float* __restrict__ diag,
    float* __restrict__ out)
{
    __shared__ float sm[4];
    int gtid = blockIdx.x * 256 + threadIdx.x;
    float s = 0.0f;
    for (int row = gtid; row < NROWS; row += 32 * 256) {
        float t = 0.0f;
#pragma unroll
        for (int g = 0; g < SEGS; ++g) t += lpart[(size_t)g * NROWS + row];
        s += LN2f * log2f(t) - INVT * diag[row];
    }
    for (int m = 1; m < 64; m <<= 1) s += __shfl_xor(s, m, 64);
    int wave = threadIdx.x >> 6, lane = threadIdx.x & 63;
    if (lane == 0) sm[wave] = s;
    __syncthreads();
    if (threadIdx.x == 0) {
        float tot = sm[0] + sm[1] + sm[2] + sm[3];
        atomicAdd(out, tot * (1.0f / NROWS));
    }
}

extern "C" void kernel_launch(void* const* d_in, const int* in_sizes, int n_in,
                              void* d_out, int out_size, void* d_ws, size_t ws_size,
                              hipStream_t stream) {
    const float* fl = (const float*)d_in[0];
    const float* fg = (const float*)d_in[1];
    float* out = (float*)d_out;

    char* ws = (char*)d_ws;
    unsigned char* A = (unsigned char*)ws;                         // 16384*128 = 2 MB (fp4)
    unsigned char* B = A + (size_t)NROWS * DB;                     // 2 MB (fp4, staging layout)
    float* diag  = (float*)(ws + 2 * (size_t)NROWS * DB);          // 64 KB
    float* lpart = diag + NROWS;                                   // SEGS*N*4 = 512 KB

    norm_diag_kernel<<<NROWS / 4, 256, 0, stream>>>(fl, fg, A, B, diag, out);
    sim_lse_kernel<<<dim3(SEGS, NROWS / 128), 256, 0, stream>>>(A, B, lpart);
    reduce_kernel<<<32, 256, 0, stream>>>(lpart, diag, out);
}

// Round 11
// 122.801 us; speedup vs baseline: 1.1905x; 1.1000x over previous
//
#include <hip/hip_runtime.h>
#include <hip/hip_bf16.h>

#define NROWS 16384
#define DIM   256
#define DB    (DIM / 2)               // 128 bytes per fp4 row
#define SEGS  6
#define BN    128                     // staged tile: 128 cols x 256 k (fp4) = 16 KB
#define TB    (BN * DB)               // 16384 bytes per staged tile
#define INVT  14.285714285714286f
#define C1f   20.60992915555662f      // log2(e)/0.07 ; A is pre-scaled by this
#define LN2f  0.6931471805599453f

typedef __attribute__((ext_vector_type(8)))  int   int8v;    // MFMA operand (fp4 uses low 4 regs)
typedef __attribute__((ext_vector_type(16))) float f32x16;   // 32x32 MFMA accumulator

#define SCA 0x7F7F7F7Fu   // E8M0 = 2^0   (A scale; A pre-scaled by C1, sigma~1.29)
#define SCB 0x7B7B7B7Bu   // E8M0 = 2^-4  (B scale; B pre-multiplied by 16, sigma~1.0)

// fp4 e2m1 RNE quantize: codes 0..7 = {0, .5, 1, 1.5, 2, 3, 4, 6} (monotonic), bit3 = sign
__device__ __forceinline__ unsigned fp4q(float v) {
    float a = fabsf(v);
    unsigned s = (__float_as_uint(v) >> 28) & 0x8u;
    unsigned idx = (unsigned)(a >= 0.25f) + (a >= 0.75f) + (a >= 1.25f) + (a >= 1.75f)
                 + (a >= 2.5f) + (a >= 3.5f) + (a >= 5.0f);
    return s | idx;
}

// Kernel 1: L2-normalize (fp32); emit fp4 A (row-major, xC1) and fp4 B (x16) in the
// DMA staging layout, plus exact fp32 diagonal. One wave per row; lane holds 4 values
// = 16 bits per matrix.
// B layout (16B chunks of the 128B fp4 row): chunk(col,kcb4) = (col>>7)*1024
//     + ((col>>6)&1)*512 + kcb4*64 + (col&63),   kcb4 = 16B chunk along K (0..7)
__global__ __launch_bounds__(256) void norm_diag_kernel(
    const float* __restrict__ fl, const float* __restrict__ fg,
    unsigned char* __restrict__ A, unsigned char* __restrict__ B,
    float* __restrict__ diag, float* __restrict__ out)
{
    int tid  = threadIdx.x;
    int wave = tid >> 6, lane = tid & 63;
    int row  = blockIdx.x * 4 + wave;
    if (blockIdx.x == 0 && tid == 0) out[0] = 0.0f;   // zero accumulator for final atomicAdd

    float4 xl = ((const float4*)(fl + (size_t)row * DIM))[lane];
    float4 xg = ((const float4*)(fg + (size_t)row * DIM))[lane];
    float ssl = xl.x*xl.x + xl.y*xl.y + xl.z*xl.z + xl.w*xl.w;
    float ssg = xg.x*xg.x + xg.y*xg.y + xg.z*xg.z + xg.w*xg.w;
    for (int m = 1; m < 64; m <<= 1) {
        ssl += __shfl_xor(ssl, m, 64);
        ssg += __shfl_xor(ssg, m, 64);
    }
    float il = 1.0f / fmaxf(sqrtf(ssl), 1e-12f);
    float ig = 1.0f / fmaxf(sqrtf(ssg), 1e-12f);
    float nl0 = xl.x*il, nl1 = xl.y*il, nl2 = xl.z*il, nl3 = xl.w*il;
    float ng0 = xg.x*ig, ng1 = xg.y*ig, ng2 = xg.z*ig, ng3 = xg.w*ig;

    // A: quantize C1*nl to fp4 (scale 2^0 at MFMA); lane holds k = 4*lane..4*lane+3
    unsigned pa4 = fp4q(nl0 * C1f) | (fp4q(nl1 * C1f) << 4)
                 | (fp4q(nl2 * C1f) << 8) | (fp4q(nl3 * C1f) << 12);
    ((unsigned short*)(A + (size_t)row * DB))[lane] = (unsigned short)pa4;

    // B: quantize 16*ng to fp4 (scale 2^-4 at MFMA), store into staging layout
    unsigned pb4 = fp4q(ng0 * 16.0f) | (fp4q(ng1 * 16.0f) << 4)
                 | (fp4q(ng2 * 16.0f) << 8) | (fp4q(ng3 * 16.0f) << 12);
    {
        int kcb4 = lane >> 3;         // 16B chunk along K (0..7); lane's 2 bytes sit at (lane&7)*2
        unsigned chunk = (unsigned)((row >> 7) * 1024 + ((row >> 6) & 1) * 512
                                    + kcb4 * 64 + (row & 63));
        ((unsigned short*)B)[chunk * 8 + (lane & 7)] = (unsigned short)pb4;
    }

    float d = nl0*ng0 + nl1*ng1 + nl2*ng2 + nl3*ng3;   // exact fp32 diagonal
    for (int m = 1; m < 64; m <<= 1) d += __shfl_xor(d, m, 64);
    if (lane == 0) diag[row] = d;
}

// Kernel 2: fused sim-GEMM + fixed-max sumexp, MX-fp4 32x32x64 (fmt=4, 2x fp8 rate).
// R29: FIT THE REGISTERS, DON'T FIGHT THEM. Post-mortem synthesis: with
// launch_bounds(256,4) the unified file splits ~64 VGPR + 64 AGPR and the
// arch-VGPR side (af 32 + b 16-32 + lv 16 + addr ~12 = 76-92) ALWAYS spills
// (R26: 6.6 MB scratch, occupancy counter ~2.3 waves/SIMD not 4; R28: 24 MB,
// regressed). The kernel genuinely needs ~150 regs. This version runs at
// 3 waves/SIMD (cap 170, launch_bounds(256,3)): grid 6 segs x 128 row-blocks
// = 768 blocks = 3 blocks/CU (LDS 96 KB). ILP comes back via a 2-chain
// column-pair interleave: each tile's 4 col-units = 2 pair-slots; a slot runs
// TWO independent depth-4 MFMA chains (cols c, c+32) sharing af, while exp-ing
// the previous pair's accumulators. Budget: VGPR ~92 (af 32 + b 4x8 + lv 16 +
// addr) + AGPR 64 (4 accs) = ~156 <= 170 -> ZERO spill, honest 3 waves/SIMD,
// 3 waves x 2 chains = 6 independent MFMA streams per SIMD.
// 128 tiles don't divide by 6 segs: segs 0-1 get 22 tiles, segs 2-5 get 21.
__global__ __launch_bounds__(256, 3) void sim_lse_kernel(
    const unsigned char* __restrict__ A, const unsigned char* __restrict__ B,
    float* __restrict__ lpart)
{
    __shared__ __align__(16) unsigned char bt[2 * TB];   // 2 x 16 KB double buffer

    int tid  = threadIdx.x;
    int lane = tid & 63;
    int l31  = lane & 31, half = lane >> 5;
    int wave = tid >> 6;
    int seg  = blockIdx.x;                        // 0..5
    int nt   = 21 + (seg < 2 ? 1 : 0);            // tiles this seg
    int T0   = seg * 21 + (seg < 2 ? seg : 2);    // first tile
    int rowBase = blockIdx.y * 128 + wave * 32;   // 32 rows per wave

    // LDS read base; unit offsets are 16-bit immediates:
    // addr = vb + bufo(16384) + s64*8192 + c*512 + kk*2048
    unsigned vb = (unsigned)(l31 * 16 + half * 1024);

    const int4 zero4 = make_int4(0, 0, 0, 0);

    // Preload A fragments: lane(l31,half) holds A[m=rowBase+l31][k = kk*64 + half*32 + 0..31]
    // = 16 bytes of fp4; high half of the 8-reg operand is unused (fmt=4) -> zeroed once.
    int8v af[4];
    {
        const unsigned char* ap = A + (size_t)(rowBase + l31) * DB + half * 16;
#pragma unroll
        for (int kk = 0; kk < 4; ++kk) {
            ((int4*)&af[kk])[0] = *(const int4*)(ap + kk * 32);
            ((int4*)&af[kk])[1] = zero4;
        }
    }

    f32x16 lv;
    f32x16 p0, p1, q0, q1;   // two acc-pairs: compute one pair while exp-ing the other
#pragma unroll
    for (int r = 0; r < 16; ++r) {
        lv[r] = -2.0f;     // compensate the one dummy pair-epilogue (exp2(0)+exp2(0))
        q0[r] = 0.0f; q1[r] = 0.0f;
    }

    // Stage one 16 KB tile (1024 16B chunks); each thread moves 4 chunks
    auto stage = [&](int T, unsigned bufo) {
        const unsigned char* g = B + (size_t)T * TB + (unsigned)tid * 16;
        unsigned lo = bufo + (unsigned)tid * 16;
#pragma unroll
        for (int j = 0; j < 4; ++j) {
            __builtin_amdgcn_global_load_lds(
                (const __attribute__((address_space(1))) unsigned int*)(g + j * 4096),
                (__attribute__((address_space(3))) unsigned int*)&bt[lo + j * 4096],
                16, 0, 0);
        }
    };

#define MFMA4(dst, a, b, cin) \
    dst = __builtin_amdgcn_mfma_scale_f32_32x32x64_f8f6f4(a, b, cin, 4, 4, 0, SCA, 0, SCB)

    // One pair-slot: two independent depth-4 chains (cols at offA, offB) sharing af;
    // exps consume the other pair (e0,e1) fully (32 exp2+add), interleaved.
    auto slot = [&](f32x16& c0, f32x16& c1, f32x16& e0, f32x16& e1,
                    unsigned ab, unsigned offA, unsigned offB) {
#pragma unroll
        for (int r = 0; r < 16; ++r) { c0[r] = 0.0f; c1[r] = 0.0f; }
        int8v b0, b1, b2, b3;
        ((int4*)&b0)[1] = zero4; ((int4*)&b1)[1] = zero4;
        ((int4*)&b2)[1] = zero4; ((int4*)&b3)[1] = zero4;
        ((int4*)&b0)[0] = *(const int4*)&bt[ab + offA];            // chain0 kk=0
        ((int4*)&b1)[0] = *(const int4*)&bt[ab + offB];            // chain1 kk=0
        MFMA4(c0, af[0], b0, c0);
        MFMA4(c1, af[0], b1, c1);
#pragma unroll
        for (int r = 0; r < 8; ++r)  lv[r] += __builtin_amdgcn_exp2f(e0[r]);
        ((int4*)&b2)[0] = *(const int4*)&bt[ab + offA + 2048u];    // kk=1
        ((int4*)&b3)[0] = *(const int4*)&bt[ab + offB + 2048u];
        MFMA4(c0, af[1], b2, c0);
        MFMA4(c1, af[1], b3, c1);
#pragma unroll
        for (int r = 8; r < 16; ++r) lv[r] += __builtin_amdgcn_exp2f(e0[r]);
        ((int4*)&b0)[0] = *(const int4*)&bt[ab + offA + 4096u];    // kk=2
        ((int4*)&b1)[0] = *(const int4*)&bt[ab + offB + 4096u];
        MFMA4(c0, af[2], b0, c0);
        MFMA4(c1, af[2], b1, c1);
#pragma unroll
        for (int r = 0; r < 8; ++r)  lv[r] += __builtin_amdgcn_exp2f(e1[r]);
        ((int4*)&b2)[0] = *(const int4*)&bt[ab + offA + 6144u];    // kk=3
        ((int4*)&b3)[0] = *(const int4*)&bt[ab + offB + 6144u];
        MFMA4(c0, af[3], b2, c0);
        MFMA4(c1, af[3], b3, c1);
#pragma unroll
        for (int r = 8; r < 16; ++r) lv[r] += __builtin_amdgcn_exp2f(e1[r]);
    };

    stage(T0, 0);

    for (int t = 0; t < nt; ++t) {
        unsigned bufo = (t & 1) ? (unsigned)TB : 0u;
        __syncthreads();   // drains own tile-t DMA (in flight a full tile), syncs waves

        if (t + 1 < nt)
            stage(T0 + t + 1, (t & 1) ? 0u : (unsigned)TB);

        unsigned ab = vb + bufo;
        slot(p0, p1, q0, q1, ab, 0u,    512u);    // compute cols 0-63,  exp prev pair
        slot(q0, q1, p0, p1, ab, 8192u, 8704u);   // compute cols 64-127, exp pair just done
    }
    // final epilogue: exp the last computed pair (q0,q1)
#pragma unroll
    for (int r = 0; r < 16; ++r)
        lv[r] += __builtin_amdgcn_exp2f(q0[r]) + __builtin_amdgcn_exp2f(q1[r]);

    // Sum across the 32 column-lanes
#pragma unroll
    for (int r = 0; r < 16; ++r) {
        float v = lv[r];
        v += __shfl_xor(v, 1, 64);
        v += __shfl_xor(v, 2, 64);
        v += __shfl_xor(v, 4, 64);
        v += __shfl_xor(v, 8, 64);
        v += __shfl_xor(v, 16, 64);
        lv[r] = v;
    }
    if (l31 == 0) {
#pragma unroll
        for (int r = 0; r < 16; ++r) {
            int row = rowBase + (r & 3) + 8*(r >> 2) + 4*half;
            lpart[(size_t)seg * NROWS + row] = lv[r];
        }
    }
#undef MFMA4
}

// Kernel 3: loss_i = -invT*diag_i + ln2*log2(sum_seg l_part), then mean via atomicAdd.
__global__ __launch_bounds__(256) void reduce_kernel(
    const float* __restrict__ lpart, const float* __restrict__ diag,
    float* __restrict__ out)
{
    __shared__ float sm[4];
    int gtid = blockIdx.x * 256 + threadIdx.x;
    float s = 0.0f;
    for (int row = gtid; row < NROWS; row += 32 * 256) {
        float t = 0.0f;
#pragma unroll
        for (int g = 0; g < SEGS; ++g) t += lpart[(size_t)g * NROWS + row];
        s += LN2f * log2f(t) - INVT * diag[row];
    }
    for (int m = 1; m < 64; m <<= 1) s += __shfl_xor(s, m, 64);
    int wave = threadIdx.x >> 6, lane = threadIdx.x & 63;
    if (lane == 0) sm[wave] = s;
    __syncthreads();
    if (threadIdx.x == 0) {
        float tot = sm[0] + sm[1] + sm[2] + sm[3];
        atomicAdd(out, tot * (1.0f / NROWS));
    }
}

extern "C" void kernel_launch(void* const* d_in, const int* in_sizes, int n_in,
                              void* d_out, int out_size, void* d_ws, size_t ws_size,
                              hipStream_t stream) {
    const float* fl = (const float*)d_in[0];
    const float* fg = (const float*)d_in[1];
    float* out = (float*)d_out;

    char* ws = (char*)d_ws;
    unsigned char* A = (unsigned char*)ws;                         // 16384*128 = 2 MB (fp4)
    unsigned char* B = A + (size_t)NROWS * DB;                     // 2 MB (fp4, staging layout)
    float* diag  = (float*)(ws + 2 * (size_t)NROWS * DB);          // 64 KB
    float* lpart = diag + NROWS;                                   // SEGS*N*4 = 384 KB

    norm_diag_kernel<<<NROWS / 4, 256, 0, stream>>>(fl, fg, A, B, diag, out);
    sim_lse_kernel<<<dim3(SEGS, NROWS / 128), 256, 0, stream>>>(A, B, lpart);
    reduce_kernel<<<32, 256, 0, stream>>>(lpart, diag, out);
}